// Round 2
// baseline (261.669 us; speedup 1.0000x reference)
//
#include <hip/hip_runtime.h>
#include <math.h>

// Problem constants
#define BB 8
#define LL 2048
#define DD 512
#define NST 32
#define CHUNK 128
#define MCH (LL/CHUNK)   // 16 chunks
#define DIRS 2

// ws layout (float offsets)
constexpr size_t XT_OFF = 0;                                  // B*D*L = 8388608
constexpr size_t SRE    = XT_OFF + (size_t)BB*DD*LL;          // B*D*2*M*N = 4194304
constexpr size_t SIM    = SRE + (size_t)BB*DD*DIRS*MCH*NST;
constexpr size_t WRE    = SIM + (size_t)BB*DD*DIRS*MCH*NST;   // D*N = 16384
constexpr size_t WIM    = WRE + (size_t)DD*NST;
constexpr size_t WCRE   = WIM + (size_t)DD*NST;
constexpr size_t WCIM   = WCRE + (size_t)DD*NST;
constexpr size_t CRE    = WCIM + (size_t)DD*NST;              // 2*D*N = 32768
constexpr size_t CIM    = CRE + (size_t)DIRS*DD*NST;
// total = CIM + 32768 floats = ~67.6 MB

// ---------------------------------------------------------------------------
// Kernel P: per (d,n) compute w = exp(a*dt), wC = w^CHUNK, and per-dir scaled
// coefficients c~ = coeffs * (w-1)/a. All complex, stored as separate re/im.
__global__ __launch_bounds__(256) void kparams(
    const float* __restrict__ log_dt, const float* __restrict__ log_a_real,
    const float* __restrict__ a_imag, const float* __restrict__ coeffs,
    float* __restrict__ ws) {
  int i = blockIdx.x * 256 + threadIdx.x;     // (d,n)
  if (i >= DD * NST) return;
  int d = i / NST;
  float dt = expf(log_dt[d]);
  float ar = -expf(log_a_real[i]);
  float ai = a_imag[i];
  float dar = ar * dt, dai = ai * dt;
  float er = expf(dar);
  float wr = er * cosf(dai), wi = er * sinf(dai);
  ws[WRE + i] = wr; ws[WIM + i] = wi;
  float erc = expf(dar * (float)CHUNK);
  ws[WCRE + i] = erc * cosf(dai * (float)CHUNK);
  ws[WCIM + i] = erc * sinf(dai * (float)CHUNK);
  // q = (w - 1) / a  (complex division)
  float m2 = ar * ar + ai * ai;
  float numr = wr - 1.0f, numi = wi;
  float qr = (numr * ar + numi * ai) / m2;
  float qi = (numi * ar - numr * ai) / m2;
  #pragma unroll
  for (int dir = 0; dir < DIRS; ++dir) {
    float cr0 = coeffs[((size_t)(dir * DD + d) * NST + (i % NST)) * 2 + 0];
    float ci0 = coeffs[((size_t)(dir * DD + d) * NST + (i % NST)) * 2 + 1];
    ws[CRE + (size_t)dir * DD * NST + i] = cr0 * qr - ci0 * qi;
    ws[CIM + (size_t)dir * DD * NST + i] = cr0 * qi + ci0 * qr;
  }
}

// ---------------------------------------------------------------------------
// Kernel T: transpose (B,L,D) -> (B,D,L), coalesced both sides via LDS tile.
__global__ __launch_bounds__(256) void ktranspose(
    const float* __restrict__ x, float* __restrict__ xT) {
  __shared__ float tile[32][33];
  int lx = threadIdx.x, ly = threadIdx.y;       // 32 x 8
  int lt = blockIdx.x, dtile = blockIdx.y, b = blockIdx.z;
  int l0 = lt * 32, d0 = dtile * 32;
  #pragma unroll
  for (int k = 0; k < 4; ++k)
    tile[ly * 4 + k][lx] = x[((size_t)b * LL + l0 + ly * 4 + k) * DD + d0 + lx];
  __syncthreads();
  #pragma unroll
  for (int k = 0; k < 4; ++k)
    xT[((size_t)b * DD + d0 + ly * 4 + k) * LL + l0 + lx] = tile[lx][ly * 4 + k];
}

// ---------------------------------------------------------------------------
// Kernel 1: per-(b,d) local Horner sums, BOTH dirs fused (row staged once).
// local[dir,m] = sum_j w^(C-1-j) x_dir[m*C+j], x_bwd = reversed row.
// 256 threads = 32 n x 8 slots; 4 outer iterations cover 32 (dir,m) items.
// Within a wave, items {2k+8mo, 2k+1+8mo} share the same dir-16-block ->
// dir is wave-uniform, no divergence.
#define K1PAD 132
__global__ __launch_bounds__(256) void klocal(
    const float* __restrict__ xT, float* __restrict__ ws) {
  __shared__ float xs[MCH * K1PAD];
  int bid = blockIdx.x;              // B*D
  int d = bid & (DD - 1);
  int b = bid >> 9;
  const float* xrow = xT + ((size_t)b * DD + d) * LL;
  int tid = threadIdx.x;
  for (int it = 0; it < LL / 256; ++it) {
    int idx = it * 256 + tid;
    xs[(idx >> 7) * K1PAD + (idx & 127)] = xrow[idx];
  }
  __syncthreads();
  int n = tid & 31, slot = tid >> 5;
  int i = d * NST + n;
  float wr = ws[WRE + i], wi = ws[WIM + i];
  for (int mo = 0; mo < 4; ++mo) {
    int item = slot + mo * 8;        // 0..31
    int m = item & 15, dir = item >> 4;
    float sr = 0.f, si = 0.f;
    const float* xc = (dir == 0) ? (xs + m * K1PAD) : (xs + (MCH - 1 - m) * K1PAD);
    #pragma unroll 4
    for (int j = 0; j < CHUNK; ++j) {
      float xv = (dir == 0) ? xc[j] : xc[127 - j];
      float nr = fmaf(wr, sr, fmaf(-wi, si, xv));
      float ni = fmaf(wr, si, wi * sr);
      sr = nr; si = ni;
    }
    size_t sbase = (((size_t)b * DD + d) * DIRS + dir) * MCH * NST;
    ws[SRE + sbase + (size_t)m * NST + n] = sr;
    ws[SIM + sbase + (size_t)m * NST + n] = si;
  }
}

// ---------------------------------------------------------------------------
// Kernel 2: scan over chunk boundaries. Thread per (b,d,dir,n).
// Rewrites S[m] from "local sum of chunk m" to "state entering chunk m".
__global__ __launch_bounds__(256) void kscan(float* __restrict__ ws) {
  int g = blockIdx.x * 256 + threadIdx.x;   // B*D*2*N = 524288 total
  int n = g & 31;
  int dir = (g >> 5) & 1;
  int d = (g >> 6) & (DD - 1);
  int b = g >> 15;
  int i = d * NST + n;
  float wcr = ws[WCRE + i], wci = ws[WCIM + i];
  size_t base = (((size_t)b * DD + d) * DIRS + dir) * MCH * NST + n;
  float sr = 0.f, si = 0.f;
  #pragma unroll
  for (int m = 0; m < MCH; ++m) {
    size_t o = base + (size_t)m * NST;
    float tr = ws[SRE + o], ti = ws[SIM + o];
    ws[SRE + o] = sr; ws[SIM + o] = si;
    float nr = fmaf(wcr, sr, fmaf(-wci, si, tr));
    float ni = fmaf(wcr, si, fmaf(wci, sr, ti));
    sr = nr; si = ni;
  }
}

// ---------------------------------------------------------------------------
// Kernel 3: outputs. Block = (b, chunk m, 32-channel tile). 256 threads:
// tid = dloc*8 + dir*4 + g ; each thread owns 8 states (n = g*8..g*8+7).
// Runs the in-chunk recurrence from the boundary state; 2x shfl_xor reduces
// over the 4 n-groups; fwd chunk m and bwd chunk (M-1-m) both produce output
// rows l in [m*C, (m+1)*C), fused with the residual x*scale. Coalesced write.
#define PAD3 133
__global__ __launch_bounds__(256) void kout(
    const float* __restrict__ xT, const float* __restrict__ ws,
    const float* __restrict__ input_scale, float* __restrict__ out) {
  __shared__ float xs[32 * PAD3];
  __shared__ float yf[32 * PAD3];
  __shared__ float yb[32 * PAD3];
  int dtile = blockIdx.x;   // D/32 = 16
  int m = blockIdx.y;       // MCH
  int b = blockIdx.z;
  int tid = threadIdx.x;
  for (int it = 0; it < 16; ++it) {
    int idx = it * 256 + tid;
    int ds = idx >> 7, js = idx & 127;
    xs[ds * PAD3 + js] = xT[((size_t)b * DD + dtile * 32 + ds) * LL + m * CHUNK + js];
  }
  __syncthreads();
  int dloc = tid >> 3, dir = (tid >> 2) & 1, g = tid & 3;
  int d = dtile * 32 + dloc;
  int nb = g * 8;
  int meff = dir ? (MCH - 1 - m) : m;
  size_t sbase = ((((size_t)b * DD + d) * DIRS + dir) * MCH + meff) * NST + nb;
  size_t pbase = (size_t)d * NST + nb;
  float wr[8], wi[8], cr[8], ci[8], sr[8], si[8];
  #pragma unroll
  for (int k = 0; k < 8; ++k) {
    wr[k] = ws[WRE + pbase + k];
    wi[k] = ws[WIM + pbase + k];
    cr[k] = ws[CRE + (size_t)dir * DD * NST + pbase + k];
    ci[k] = ws[CIM + (size_t)dir * DD * NST + pbase + k];
    sr[k] = ws[SRE + sbase + k];
    si[k] = ws[SIM + sbase + k];
  }
  const float* xrow = xs + dloc * PAD3;
  float* yrow = (dir ? yb : yf) + dloc * PAD3;
  for (int j = 0; j < CHUNK; ++j) {
    float xv = dir ? xrow[127 - j] : xrow[j];
    float acc = 0.f;
    #pragma unroll
    for (int k = 0; k < 8; ++k) {
      float nr = fmaf(wr[k], sr[k], fmaf(-wi[k], si[k], xv));
      float ni = fmaf(wr[k], si[k], wi[k] * sr[k]);
      sr[k] = nr; si[k] = ni;
      acc = fmaf(cr[k], nr, fmaf(-ci[k], ni, acc));
    }
    acc += __shfl_xor(acc, 1);
    acc += __shfl_xor(acc, 2);
    if (g == 0) yrow[j] = 2.f * acc;
  }
  __syncthreads();
  for (int it = 0; it < 16; ++it) {
    int idx = it * 256 + tid;
    int jj = idx >> 5, ds = idx & 31;
    float xv = xs[ds * PAD3 + jj];
    float val = yf[ds * PAD3 + jj] + yb[ds * PAD3 + (127 - jj)]
              + xv * input_scale[dtile * 32 + ds];
    out[((size_t)b * LL + m * CHUNK + jj) * DD + dtile * 32 + ds] = val;
  }
}

// ---------------------------------------------------------------------------
extern "C" void kernel_launch(void* const* d_in, const int* in_sizes, int n_in,
                              void* d_out, int out_size, void* d_ws, size_t ws_size,
                              hipStream_t stream) {
  const float* x           = (const float*)d_in[0];
  const float* log_dt      = (const float*)d_in[1];
  const float* log_a_real  = (const float*)d_in[2];
  const float* a_imag      = (const float*)d_in[3];
  const float* coeffs      = (const float*)d_in[4];
  const float* input_scale = (const float*)d_in[5];
  float* out = (float*)d_out;
  float* ws  = (float*)d_ws;

  kparams<<<(DD * NST + 255) / 256, 256, 0, stream>>>(log_dt, log_a_real, a_imag, coeffs, ws);
  ktranspose<<<dim3(LL / 32, DD / 32, BB), dim3(32, 8), 0, stream>>>(x, ws + XT_OFF);
  klocal<<<BB * DD, 256, 0, stream>>>(ws + XT_OFF, ws);
  kscan<<<(BB * DD * DIRS * NST) / 256, 256, 0, stream>>>(ws);
  kout<<<dim3(DD / 32, MCH, BB), 256, 0, stream>>>(ws + XT_OFF, ws, input_scale, out);
}

// Round 4
// 139.844 us; speedup vs baseline: 1.8711x; 1.8711x over previous
//
#include <hip/hip_runtime.h>
#include <math.h>

// Problem constants
#define BB 8
#define LL 2048
#define DD 512
#define NST 32
#define CHUNK 128
#define MCH 16
#define DIRS 2

typedef _Float16 f16x8 __attribute__((ext_vector_type(8)));
typedef float    f32x4 __attribute__((ext_vector_type(4)));

// ws byte layout
// X16:  [d][bm(128)][j(128)] f16 rows of 256B   -> 512*128*128*2 = 16 MiB
// Ytmp: [d][bm(128)][jj(128)] f16 rows of 256B  -> 16 MiB
#define WS_X16_BYTES  ((size_t)DD*128*128*2)
#define WS_YT_OFF     WS_X16_BYTES

// ---------------------------------------------------------------------------
// ktrans16: x (B,L,D) fp32 -> X16 [d][b*16+m][j] f16 (chunked-transposed)
__global__ __launch_bounds__(256) void ktrans16(
    const float* __restrict__ x, _Float16* __restrict__ X16) {
  __shared__ float tile[32][33];
  int lx = threadIdx.x, ly = threadIdx.y;       // 32 x 8
  int lt = blockIdx.x, dt2 = blockIdx.y, b = blockIdx.z;
  int l0 = lt * 32, d0 = dt2 * 32;
  #pragma unroll
  for (int k = 0; k < 4; ++k)
    tile[ly * 4 + k][lx] = x[((size_t)b * LL + l0 + ly * 4 + k) * DD + d0 + lx];
  __syncthreads();
  int m = l0 >> 7, j0 = l0 & 127;
  #pragma unroll
  for (int k = 0; k < 4; ++k) {
    int dd = ly * 4 + k;
    X16[((size_t)(d0 + dd) * 128 + b * 16 + m) * 128 + j0 + lx] =
        (_Float16)tile[lx][dd];
  }
}

// ---------------------------------------------------------------------------
// kfused: per-d block. Phases:
//  P0 params -> LDS tail; P1 load X + build V + kvec partials; P1d kvec reduce
//  P2 MFMA S^T = X * V^T ; P3 acc->Sl(LDS fp32) ; P4 16-step scan -> S0 (f16)
//  P5 build Tcomb (lower=k0, upper=k1 reversed-bwd) + Ecomb ; P6 MFMA Y
//  P7 Y->LDS f16 -> flush to Ytmp
#define ROWB 272           // padded f16 row: 128*2 + 16 pad (16B aligned)
#define SLSTR 528          // Sl fp32 row: 132 dwords
#define SM_X   0
#define SM_R1  34816       // V, later Tcomb
#define SM_R2  69632       // kvec partials, later Ecomb
#define SM_SL  34816       // fp32 [128][132] spans R1+R2 (67584B)
#define SM_S0  104448      // [bm][k(128)] f16: 0:32 s0f_re |32:64 s0f_im |64:96 s0b_re |96:128 s0b_im
#define SM_TAIL 139264     // params + kvec (fp32)
// tail float offsets: 0 ardt |32 aidt |64 wr |96 wi |128 wcr |160 wci
//                     192 c0r |224 c0i |256 c1r |288 c1i |320 k0[128] |448 k1[128]

__global__ __launch_bounds__(256, 1) void kfused(
    const _Float16* __restrict__ X16,
    const float* __restrict__ log_dt, const float* __restrict__ log_a_real,
    const float* __restrict__ a_imag, const float* __restrict__ coeffs,
    _Float16* __restrict__ Ytmp) {
  __shared__ char sm[141568];
  float* tailf = (float*)(sm + SM_TAIL);
  int d = blockIdx.x, t = threadIdx.x;

  // ---- P0: per-n parameters
  if (t < 32) {
    int n = t;
    float dt = expf(log_dt[d]);
    float ar = -expf(log_a_real[d * 32 + n]);
    float ai = a_imag[d * 32 + n];
    float ardt = ar * dt, aidt = ai * dt;
    tailf[n] = ardt; tailf[32 + n] = aidt;
    float er = expf(ardt);
    float wr = er * cosf(aidt), wi = er * sinf(aidt);
    tailf[64 + n] = wr; tailf[96 + n] = wi;
    float ec = expf(ardt * 128.f);
    tailf[128 + n] = ec * cosf(aidt * 128.f);
    tailf[160 + n] = ec * sinf(aidt * 128.f);
    float m2 = ar * ar + ai * ai;
    float qr = ((wr - 1.f) * ar + wi * ai) / m2;
    float qi = (wi * ar - (wr - 1.f) * ai) / m2;
    #pragma unroll
    for (int dir = 0; dir < 2; ++dir) {
      float cr = coeffs[((size_t)(dir * DD + d) * NST + n) * 2 + 0];
      float ci = coeffs[((size_t)(dir * DD + d) * NST + n) * 2 + 1];
      tailf[192 + dir * 64 + n] = cr * qr - ci * qi;
      tailf[224 + dir * 64 + n] = cr * qi + ci * qr;
    }
  }
  __syncthreads();

  // ---- P1: load X (32KB), build V (R1), kvec partials (R2)
  {
    const uint4* src = (const uint4*)(X16 + (size_t)d * 16384);
    #pragma unroll
    for (int i = 0; i < 8; ++i) {
      int u = t + i * 256;            // 2048 uint4
      int r = u >> 4, c16 = u & 15;
      *(uint4*)(sm + SM_X + r * ROWB + c16 * 16) = src[u];
    }
  }
  {
    // V rows: [0:32) Re w^(127-j) | [32:64) Im | [64:96) Re w^j | [96:128) Im
    int r = t >> 1, jh = t & 1, n = r & 31, quad = r >> 5;
    float wr = tailf[64 + n], wi = tailf[96 + n];
    float ardt = tailf[n], aidt = tailf[32 + n];
    int fwd = (quad < 2);
    float p0 = fwd ? (float)(64 * (1 - jh)) : (float)(64 * jh);
    float e = expf(ardt * p0);
    float sr = e * cosf(aidt * p0), si = e * sinf(aidt * p0);
    _Float16* row = (_Float16*)(sm + SM_R1 + r * ROWB);
    for (int q = 0; q < 64; ++q) {
      int j = fwd ? (jh * 64 + 63 - q) : (jh * 64 + q);
      row[j] = (_Float16)((quad & 1) ? si : sr);
      float a = sr * wr - si * wi, b2 = sr * wi + si * wr;
      sr = a; si = b2;
    }
  }
  if (t < 64) {  // kvec partials: partial[dir*32+n][delta] = Re(c~ w^delta)
    int dir = t >> 5, n = t & 31;
    float wr = tailf[64 + n], wi = tailf[96 + n];
    float sr = tailf[192 + dir * 64 + n], si = tailf[224 + dir * 64 + n];
    float* prow = (float*)(sm + SM_R2) + t * 132;
    for (int q = 0; q < 128; ++q) {
      prow[q] = sr;
      float a = sr * wr - si * wi, b2 = sr * wi + si * wr;
      sr = a; si = b2;
    }
  }
  __syncthreads();
  { // P1d: reduce kvec over n -> tail
    int dir = t >> 7, dl = t & 127;
    const float* pp = (float*)(sm + SM_R2) + dir * 32 * 132;
    float s = 0.f;
    #pragma unroll
    for (int n2 = 0; n2 < 32; ++n2) s += pp[n2 * 132 + dl];
    tailf[320 + dir * 128 + dl] = 2.f * s;
  }
  __syncthreads();

  // ---- P2: MFMA  Sl^T[bm][ns] = sum_j X[bm][j] * V[ns][j]
  int wv = t >> 6, lane = t & 63;
  int rbase = wv * 32;
  int arow = lane & 15, kg = lane >> 4;   // kg 0..3
  f32x4 acc[2][8];
  #pragma unroll
  for (int tr = 0; tr < 2; ++tr)
    #pragma unroll
    for (int tc = 0; tc < 8; ++tc) acc[tr][tc] = (f32x4){0.f, 0.f, 0.f, 0.f};
  #pragma unroll
  for (int ks = 0; ks < 4; ++ks) {
    f16x8 a0 = *(const f16x8*)(sm + SM_X + (rbase + arow) * ROWB + ks * 64 + kg * 16);
    f16x8 a1 = *(const f16x8*)(sm + SM_X + (rbase + 16 + arow) * ROWB + ks * 64 + kg * 16);
    #pragma unroll
    for (int tc = 0; tc < 8; ++tc) {
      f16x8 bf = *(const f16x8*)(sm + SM_R1 + (tc * 16 + arow) * ROWB + ks * 64 + kg * 16);
      acc[0][tc] = __builtin_amdgcn_mfma_f32_16x16x32_f16(a0, bf, acc[0][tc], 0, 0, 0);
      acc[1][tc] = __builtin_amdgcn_mfma_f32_16x16x32_f16(a1, bf, acc[1][tc], 0, 0, 0);
    }
  }
  __syncthreads();
  // ---- P3: acc -> Sl (fp32)
  #pragma unroll
  for (int tr = 0; tr < 2; ++tr)
    #pragma unroll
    for (int tc = 0; tc < 8; ++tc)
      #pragma unroll
      for (int rg = 0; rg < 4; ++rg) {
        int row = rbase + tr * 16 + kg * 4 + rg;
        int col = tc * 16 + arow;
        *(float*)(sm + SM_SL + row * SLSTR + col * 4) = acc[tr][tc][rg];
      }
  __syncthreads();

  // ---- P4: inter-chunk scan (writes entering states to S0, f16)
  {
    int b = t >> 5, n = t & 31;
    float wcr = tailf[128 + n], wci = tailf[160 + n];
    float sr = 0.f, si = 0.f;
    for (int m = 0; m < 16; ++m) {            // forward
      _Float16* s0r = (_Float16*)(sm + SM_S0 + (b * 16 + m) * ROWB);
      s0r[n] = (_Float16)sr; s0r[32 + n] = (_Float16)si;
      const float* sl = (const float*)(sm + SM_SL + (b * 16 + m) * SLSTR);
      float a = wcr * sr - wci * si + sl[n];
      float b2 = wcr * si + wci * sr + sl[32 + n];
      sr = a; si = b2;
    }
    sr = 0.f; si = 0.f;
    for (int mm = 15; mm >= 0; --mm) {        // backward (rev-chunk order)
      _Float16* s0r = (_Float16*)(sm + SM_S0 + (b * 16 + mm) * ROWB);
      s0r[64 + n] = (_Float16)sr; s0r[96 + n] = (_Float16)si;
      const float* sl = (const float*)(sm + SM_SL + (b * 16 + mm) * SLSTR);
      float a = wcr * sr - wci * si + sl[64 + n];
      float b2 = wcr * si + wci * sr + sl[96 + n];
      sr = a; si = b2;
    }
  }
  __syncthreads();

  // ---- P5: build Tcomb (R1) and Ecomb (R2)
  {
    float k00 = tailf[320], k10 = tailf[448];
    for (int q = 0; q < 32; ++q) {
      int pid = t + q * 256;                  // 8192 f16-pairs
      int r = pid >> 6, cp = pid & 63, c = cp * 2;
      float v0 = (c < r) ? tailf[320 + r - c]
               : (c > r) ? tailf[448 + c - r] : (k00 + k10);
      int c1 = c + 1;
      float v1 = (c1 < r) ? tailf[320 + r - c1]
               : (c1 > r) ? tailf[448 + c1 - r] : (k00 + k10);
      union { _Float16 h[2]; unsigned u; } pk;
      pk.h[0] = (_Float16)v0; pk.h[1] = (_Float16)v1;
      *(unsigned*)(sm + SM_R1 + r * ROWB + c * 2) = pk.u;
    }
  }
  {
    // Ecomb[jj][k]: k<32: 2Re(c0~ w^(jj+1)) |32..63: -2Im | 64..95: 2Re(c1~ w^(128-jj)) |96..127: -2Im
    int k = t >> 1, jh = t & 1;
    int dir = k >> 6, comp = (k >> 5) & 1, n = k & 31;
    float ardt = tailf[n], aidt = tailf[32 + n];
    float wr = tailf[64 + n], wi = tailf[96 + n];
    float cr = tailf[192 + dir * 64 + n], ci = tailf[224 + dir * 64 + n];
    float p0 = (dir == 0) ? (float)(jh * 64 + 1) : (float)(65 - 64 * jh);
    float e = expf(ardt * p0);
    float pr = e * cosf(aidt * p0), pi = e * sinf(aidt * p0);
    float sr = cr * pr - ci * pi, si = cr * pi + ci * pr;
    for (int q = 0; q < 64; ++q) {
      int jj = (dir == 0) ? (jh * 64 + q) : (jh * 64 + 63 - q);
      float v = (comp == 0) ? 2.f * sr : -2.f * si;
      *(_Float16*)(sm + SM_R2 + jj * ROWB + k * 2) = (_Float16)v;
      float a = sr * wr - si * wi, b2 = sr * wi + si * wr;
      sr = a; si = b2;
    }
  }
  __syncthreads();

  // ---- P6: MFMA  Y[bm][jj] = sum_j X[bm][j]*Tcomb[jj][j] + sum_k S0[bm][k]*Ecomb[jj][k]
  f32x4 acc2[2][8];
  #pragma unroll
  for (int tr = 0; tr < 2; ++tr)
    #pragma unroll
    for (int tc = 0; tc < 8; ++tc) acc2[tr][tc] = (f32x4){0.f, 0.f, 0.f, 0.f};
  #pragma unroll
  for (int ks = 0; ks < 4; ++ks) {
    f16x8 a0 = *(const f16x8*)(sm + SM_X + (rbase + arow) * ROWB + ks * 64 + kg * 16);
    f16x8 a1 = *(const f16x8*)(sm + SM_X + (rbase + 16 + arow) * ROWB + ks * 64 + kg * 16);
    #pragma unroll
    for (int tc = 0; tc < 8; ++tc) {
      f16x8 bf = *(const f16x8*)(sm + SM_R1 + (tc * 16 + arow) * ROWB + ks * 64 + kg * 16);
      acc2[0][tc] = __builtin_amdgcn_mfma_f32_16x16x32_f16(a0, bf, acc2[0][tc], 0, 0, 0);
      acc2[1][tc] = __builtin_amdgcn_mfma_f32_16x16x32_f16(a1, bf, acc2[1][tc], 0, 0, 0);
    }
  }
  #pragma unroll
  for (int ks = 0; ks < 4; ++ks) {
    f16x8 a0 = *(const f16x8*)(sm + SM_S0 + (rbase + arow) * ROWB + ks * 64 + kg * 16);
    f16x8 a1 = *(const f16x8*)(sm + SM_S0 + (rbase + 16 + arow) * ROWB + ks * 64 + kg * 16);
    #pragma unroll
    for (int tc = 0; tc < 8; ++tc) {
      f16x8 bf = *(const f16x8*)(sm + SM_R2 + (tc * 16 + arow) * ROWB + ks * 64 + kg * 16);
      acc2[0][tc] = __builtin_amdgcn_mfma_f32_16x16x32_f16(a0, bf, acc2[0][tc], 0, 0, 0);
      acc2[1][tc] = __builtin_amdgcn_mfma_f32_16x16x32_f16(a1, bf, acc2[1][tc], 0, 0, 0);
    }
  }
  // ---- P7: Y -> LDS f16 (own 32-row band of X region), then flush
  #pragma unroll
  for (int tr = 0; tr < 2; ++tr)
    #pragma unroll
    for (int tc = 0; tc < 8; ++tc)
      #pragma unroll
      for (int rg = 0; rg < 4; ++rg) {
        int row = rbase + tr * 16 + kg * 4 + rg;
        int col = tc * 16 + arow;
        *(_Float16*)(sm + SM_X + row * ROWB + col * 2) = (_Float16)acc2[tr][tc][rg];
      }
  __syncthreads();
  {
    char* dstb = (char*)Ytmp + (size_t)d * 32768;
    #pragma unroll
    for (int i = 0; i < 8; ++i) {
      int u = t + i * 256;
      int r = u >> 4, c16 = u & 15;
      *(uint4*)(dstb + r * 256 + c16 * 16) =
          *(const uint4*)(sm + SM_X + r * ROWB + c16 * 16);
    }
  }
}

// ---------------------------------------------------------------------------
// kcombine: out[b][l][d] = Ytmp[d][b*16+m][jj] + X16[d][b*16+m][jj]*scale[d]
// Stages both f16 rows in LDS (65-dword stride -> conflict-free column reads).
__global__ __launch_bounds__(256) void kcombine(
    const _Float16* __restrict__ Ytmp, const _Float16* __restrict__ X16,
    const float* __restrict__ input_scale, float* __restrict__ out) {
  __shared__ unsigned yl[64 * 65];
  __shared__ unsigned xl[64 * 65];
  int dg = blockIdx.x, m = blockIdx.y, b = blockIdx.z;
  int t = threadIdx.x;
  int d0 = dg * 64;
  #pragma unroll
  for (int it = 0; it < 16; ++it) {
    int idx = t + it * 256;          // 4096 dwords per buffer
    int r = idx >> 6, c = idx & 63;
    size_t rowoff = ((size_t)(d0 + r) * 128 + b * 16 + m) * 64 + c;
    yl[r * 65 + c] = ((const unsigned*)Ytmp)[rowoff];
    xl[r * 65 + c] = ((const unsigned*)X16)[rowoff];
  }
  __syncthreads();
  int dd = t & 63, jg = t >> 6;
  float sc = input_scale[d0 + dd];
  #pragma unroll
  for (int it = 0; it < 32; ++it) {
    int jj = jg * 32 + it;
    float y  = (float)(((const _Float16*)(yl + dd * 65))[jj]);
    float xv = (float)(((const _Float16*)(xl + dd * 65))[jj]);
    size_t off = ((size_t)b * LL + m * 128 + jj) * DD + d0 + dd;
    out[off] = y + xv * sc;
  }
}

// ---------------------------------------------------------------------------
extern "C" void kernel_launch(void* const* d_in, const int* in_sizes, int n_in,
                              void* d_out, int out_size, void* d_ws, size_t ws_size,
                              hipStream_t stream) {
  const float* x           = (const float*)d_in[0];
  const float* log_dt      = (const float*)d_in[1];
  const float* log_a_real  = (const float*)d_in[2];
  const float* a_imag      = (const float*)d_in[3];
  const float* coeffs      = (const float*)d_in[4];
  const float* input_scale = (const float*)d_in[5];
  float* out = (float*)d_out;
  _Float16* X16  = (_Float16*)d_ws;
  _Float16* Ytmp = (_Float16*)((char*)d_ws + WS_YT_OFF);

  ktrans16<<<dim3(LL / 32, DD / 32, BB), dim3(32, 8), 0, stream>>>(x, X16);
  kfused<<<DD, 256, 0, stream>>>(X16, log_dt, log_a_real, a_imag, coeffs, Ytmp);
  kcombine<<<dim3(DD / 64, MCH, BB), 256, 0, stream>>>(Ytmp, X16, input_scale, out);
}

// Round 7
// 138.342 us; speedup vs baseline: 1.8915x; 1.0109x over previous
//
#include <hip/hip_runtime.h>
#include <math.h>

// Problem constants
#define BB 8
#define LL 2048
#define DD 512
#define NST 32
#define CHUNK 128
#define MCH 16
#define DIRS 2

typedef _Float16 f16x8 __attribute__((ext_vector_type(8)));
typedef float    f32x4 __attribute__((ext_vector_type(4)));

// ws byte layout
// X16:  [d][bm(128)][j(128)] f16 rows of 256B -> 16 MiB
// Ytmp: [d][bm(128)][jj(128)] f16 rows of 256B -> 16 MiB
#define WS_X16_BYTES  ((size_t)DD*128*128*2)
#define WS_YT_OFF     WS_X16_BYTES

// ---------------------------------------------------------------------------
// ktrans16 (round-6 vectorized version): x (B,L,D) fp32 -> X16 [d][b*16+m][j]
// f16. 64(l) x 32(d) tiles, coalesced 128B row loads, packed 16B f16x8 stores.
__global__ __launch_bounds__(256) void ktrans16(
    const float* __restrict__ x, _Float16* __restrict__ X16) {
  __shared__ float tile[64 * 33];
  int t = threadIdx.x;
  int lt = blockIdx.x, dt2 = blockIdx.y, b = blockIdx.z;
  int l0 = lt * 64, d0 = dt2 * 32;
  #pragma unroll
  for (int it = 0; it < 8; ++it) {
    int idx = t + it * 256;
    int row = idx >> 5, c = idx & 31;
    tile[row * 33 + c] = x[((size_t)b * LL + l0 + row) * DD + d0 + c];
  }
  __syncthreads();
  int dd = t >> 3, seg = t & 7;
  union { _Float16 h[8]; uint4 v; } pk;
  #pragma unroll
  for (int qq = 0; qq < 8; ++qq)
    pk.h[qq] = (_Float16)tile[(seg * 8 + qq) * 33 + dd];
  int m = l0 >> 7, j0 = l0 & 127;
  *(uint4*)((char*)X16 + (size_t)(d0 + dd) * 32768 + (b * 16 + m) * 256 +
            (j0 + seg * 8) * 2) = pk.v;
}

// ---------------------------------------------------------------------------
// kfused — BYTE-IDENTICAL to the round-4 version that passed (absmax 0.0625).
//  P0 params -> LDS tail; P1 load X + build V + kvec partials; P1d kvec reduce
//  P2 MFMA S^T = X * V^T ; P3 acc->Sl(LDS fp32) ; P4 16-step scan -> S0 (f16)
//  P5 build Tcomb + Ecomb ; P6 MFMA Y ; P7 Y->LDS f16 -> flush to Ytmp
#define ROWB 272           // padded f16 row: 128*2 + 16 pad (16B aligned)
#define SLSTR 528          // Sl fp32 row: 132 dwords
#define SM_X   0
#define SM_R1  34816       // V, later Tcomb
#define SM_R2  69632       // kvec partials, later Ecomb
#define SM_SL  34816       // fp32 [128][132] spans R1+R2 (67584B)
#define SM_S0  104448      // [bm][k]: 0:32 s0f_re |32:64 s0f_im |64:96 s0b_re |96:128 s0b_im
#define SM_TAIL 139264     // params + kvec (fp32)
// tail float offsets: 0 ardt |32 aidt |64 wr |96 wi |128 wcr |160 wci
//                     192 c0r |224 c0i |256 c1r |288 c1i |320 k0[128] |448 k1[128]

__global__ __launch_bounds__(256, 1) void kfused(
    const _Float16* __restrict__ X16,
    const float* __restrict__ log_dt, const float* __restrict__ log_a_real,
    const float* __restrict__ a_imag, const float* __restrict__ coeffs,
    _Float16* __restrict__ Ytmp) {
  __shared__ char sm[141568];
  float* tailf = (float*)(sm + SM_TAIL);
  int d = blockIdx.x, t = threadIdx.x;

  // ---- P0: per-n parameters
  if (t < 32) {
    int n = t;
    float dt = expf(log_dt[d]);
    float ar = -expf(log_a_real[d * 32 + n]);
    float ai = a_imag[d * 32 + n];
    float ardt = ar * dt, aidt = ai * dt;
    tailf[n] = ardt; tailf[32 + n] = aidt;
    float er = expf(ardt);
    float wr = er * cosf(aidt), wi = er * sinf(aidt);
    tailf[64 + n] = wr; tailf[96 + n] = wi;
    float ec = expf(ardt * 128.f);
    tailf[128 + n] = ec * cosf(aidt * 128.f);
    tailf[160 + n] = ec * sinf(aidt * 128.f);
    float m2 = ar * ar + ai * ai;
    float qr = ((wr - 1.f) * ar + wi * ai) / m2;
    float qi = (wi * ar - (wr - 1.f) * ai) / m2;
    #pragma unroll
    for (int dir = 0; dir < 2; ++dir) {
      float cr = coeffs[((size_t)(dir * DD + d) * NST + n) * 2 + 0];
      float ci = coeffs[((size_t)(dir * DD + d) * NST + n) * 2 + 1];
      tailf[192 + dir * 64 + n] = cr * qr - ci * qi;
      tailf[224 + dir * 64 + n] = cr * qi + ci * qr;
    }
  }
  __syncthreads();

  // ---- P1: load X (32KB), build V (R1), kvec partials (R2)
  {
    const uint4* src = (const uint4*)(X16 + (size_t)d * 16384);
    #pragma unroll
    for (int i = 0; i < 8; ++i) {
      int u = t + i * 256;            // 2048 uint4
      int r = u >> 4, c16 = u & 15;
      *(uint4*)(sm + SM_X + r * ROWB + c16 * 16) = src[u];
    }
  }
  {
    // V rows: [0:32) Re w^(127-j) | [32:64) Im | [64:96) Re w^j | [96:128) Im
    int r = t >> 1, jh = t & 1, n = r & 31, quad = r >> 5;
    float wr = tailf[64 + n], wi = tailf[96 + n];
    float ardt = tailf[n], aidt = tailf[32 + n];
    int fwd = (quad < 2);
    float p0 = fwd ? (float)(64 * (1 - jh)) : (float)(64 * jh);
    float e = expf(ardt * p0);
    float sr = e * cosf(aidt * p0), si = e * sinf(aidt * p0);
    _Float16* row = (_Float16*)(sm + SM_R1 + r * ROWB);
    for (int q = 0; q < 64; ++q) {
      int j = fwd ? (jh * 64 + 63 - q) : (jh * 64 + q);
      row[j] = (_Float16)((quad & 1) ? si : sr);
      float a = sr * wr - si * wi, b2 = sr * wi + si * wr;
      sr = a; si = b2;
    }
  }
  if (t < 64) {  // kvec partials: partial[dir*32+n][delta] = Re(c~ w^delta)
    int dir = t >> 5, n = t & 31;
    float wr = tailf[64 + n], wi = tailf[96 + n];
    float sr = tailf[192 + dir * 64 + n], si = tailf[224 + dir * 64 + n];
    float* prow = (float*)(sm + SM_R2) + t * 132;
    for (int q = 0; q < 128; ++q) {
      prow[q] = sr;
      float a = sr * wr - si * wi, b2 = sr * wi + si * wr;
      sr = a; si = b2;
    }
  }
  __syncthreads();
  { // P1d: reduce kvec over n -> tail
    int dir = t >> 7, dl = t & 127;
    const float* pp = (float*)(sm + SM_R2) + dir * 32 * 132;
    float s = 0.f;
    #pragma unroll
    for (int n2 = 0; n2 < 32; ++n2) s += pp[n2 * 132 + dl];
    tailf[320 + dir * 128 + dl] = 2.f * s;
  }
  __syncthreads();

  // ---- P2: MFMA  Sl^T[bm][ns] = sum_j X[bm][j] * V[ns][j]
  int wv = t >> 6, lane = t & 63;
  int rbase = wv * 32;
  int arow = lane & 15, kg = lane >> 4;   // kg 0..3
  f32x4 acc[2][8];
  #pragma unroll
  for (int tr = 0; tr < 2; ++tr)
    #pragma unroll
    for (int tc = 0; tc < 8; ++tc) acc[tr][tc] = (f32x4){0.f, 0.f, 0.f, 0.f};
  #pragma unroll
  for (int ks = 0; ks < 4; ++ks) {
    f16x8 a0 = *(const f16x8*)(sm + SM_X + (rbase + arow) * ROWB + ks * 64 + kg * 16);
    f16x8 a1 = *(const f16x8*)(sm + SM_X + (rbase + 16 + arow) * ROWB + ks * 64 + kg * 16);
    #pragma unroll
    for (int tc = 0; tc < 8; ++tc) {
      f16x8 bf = *(const f16x8*)(sm + SM_R1 + (tc * 16 + arow) * ROWB + ks * 64 + kg * 16);
      acc[0][tc] = __builtin_amdgcn_mfma_f32_16x16x32_f16(a0, bf, acc[0][tc], 0, 0, 0);
      acc[1][tc] = __builtin_amdgcn_mfma_f32_16x16x32_f16(a1, bf, acc[1][tc], 0, 0, 0);
    }
  }
  __syncthreads();
  // ---- P3: acc -> Sl (fp32)
  #pragma unroll
  for (int tr = 0; tr < 2; ++tr)
    #pragma unroll
    for (int tc = 0; tc < 8; ++tc)
      #pragma unroll
      for (int rg = 0; rg < 4; ++rg) {
        int row = rbase + tr * 16 + kg * 4 + rg;
        int col = tc * 16 + arow;
        *(float*)(sm + SM_SL + row * SLSTR + col * 4) = acc[tr][tc][rg];
      }
  __syncthreads();

  // ---- P4: inter-chunk scan (writes entering states to S0, f16)
  {
    int b = t >> 5, n = t & 31;
    float wcr = tailf[128 + n], wci = tailf[160 + n];
    float sr = 0.f, si = 0.f;
    for (int m = 0; m < 16; ++m) {            // forward
      _Float16* s0r = (_Float16*)(sm + SM_S0 + (b * 16 + m) * ROWB);
      s0r[n] = (_Float16)sr; s0r[32 + n] = (_Float16)si;
      const float* sl = (const float*)(sm + SM_SL + (b * 16 + m) * SLSTR);
      float a = wcr * sr - wci * si + sl[n];
      float b2 = wcr * si + wci * sr + sl[32 + n];
      sr = a; si = b2;
    }
    sr = 0.f; si = 0.f;
    for (int mm = 15; mm >= 0; --mm) {        // backward (rev-chunk order)
      _Float16* s0r = (_Float16*)(sm + SM_S0 + (b * 16 + mm) * ROWB);
      s0r[64 + n] = (_Float16)sr; s0r[96 + n] = (_Float16)si;
      const float* sl = (const float*)(sm + SM_SL + (b * 16 + mm) * SLSTR);
      float a = wcr * sr - wci * si + sl[64 + n];
      float b2 = wcr * si + wci * sr + sl[96 + n];
      sr = a; si = b2;
    }
  }
  __syncthreads();

  // ---- P5: build Tcomb (R1) and Ecomb (R2)
  {
    float k00 = tailf[320], k10 = tailf[448];
    for (int q = 0; q < 32; ++q) {
      int pid = t + q * 256;                  // 8192 f16-pairs
      int r = pid >> 6, cp = pid & 63, c = cp * 2;
      float v0 = (c < r) ? tailf[320 + r - c]
               : (c > r) ? tailf[448 + c - r] : (k00 + k10);
      int c1 = c + 1;
      float v1 = (c1 < r) ? tailf[320 + r - c1]
               : (c1 > r) ? tailf[448 + c1 - r] : (k00 + k10);
      union { _Float16 h[2]; unsigned u; } pk;
      pk.h[0] = (_Float16)v0; pk.h[1] = (_Float16)v1;
      *(unsigned*)(sm + SM_R1 + r * ROWB + c * 2) = pk.u;
    }
  }
  {
    // Ecomb[jj][k]: k<32: 2Re(c0~ w^(jj+1)) |32..63: -2Im | 64..95: 2Re(c1~ w^(128-jj)) |96..127: -2Im
    int k = t >> 1, jh = t & 1;
    int dir = k >> 6, comp = (k >> 5) & 1, n = k & 31;
    float ardt = tailf[n], aidt = tailf[32 + n];
    float wr = tailf[64 + n], wi = tailf[96 + n];
    float cr = tailf[192 + dir * 64 + n], ci = tailf[224 + dir * 64 + n];
    float p0 = (dir == 0) ? (float)(jh * 64 + 1) : (float)(65 - 64 * jh);
    float e = expf(ardt * p0);
    float pr = e * cosf(aidt * p0), pi = e * sinf(aidt * p0);
    float sr = cr * pr - ci * pi, si = cr * pi + ci * pr;
    for (int q = 0; q < 64; ++q) {
      int jj = (dir == 0) ? (jh * 64 + q) : (jh * 64 + 63 - q);
      float v = (comp == 0) ? 2.f * sr : -2.f * si;
      *(_Float16*)(sm + SM_R2 + jj * ROWB + k * 2) = (_Float16)v;
      float a = sr * wr - si * wi, b2 = sr * wi + si * wr;
      sr = a; si = b2;
    }
  }
  __syncthreads();

  // ---- P6: MFMA  Y[bm][jj] = sum_j X[bm][j]*Tcomb[jj][j] + sum_k S0[bm][k]*Ecomb[jj][k]
  f32x4 acc2[2][8];
  #pragma unroll
  for (int tr = 0; tr < 2; ++tr)
    #pragma unroll
    for (int tc = 0; tc < 8; ++tc) acc2[tr][tc] = (f32x4){0.f, 0.f, 0.f, 0.f};
  #pragma unroll
  for (int ks = 0; ks < 4; ++ks) {
    f16x8 a0 = *(const f16x8*)(sm + SM_X + (rbase + arow) * ROWB + ks * 64 + kg * 16);
    f16x8 a1 = *(const f16x8*)(sm + SM_X + (rbase + 16 + arow) * ROWB + ks * 64 + kg * 16);
    #pragma unroll
    for (int tc = 0; tc < 8; ++tc) {
      f16x8 bf = *(const f16x8*)(sm + SM_R1 + (tc * 16 + arow) * ROWB + ks * 64 + kg * 16);
      acc2[0][tc] = __builtin_amdgcn_mfma_f32_16x16x32_f16(a0, bf, acc2[0][tc], 0, 0, 0);
      acc2[1][tc] = __builtin_amdgcn_mfma_f32_16x16x32_f16(a1, bf, acc2[1][tc], 0, 0, 0);
    }
  }
  #pragma unroll
  for (int ks = 0; ks < 4; ++ks) {
    f16x8 a0 = *(const f16x8*)(sm + SM_S0 + (rbase + arow) * ROWB + ks * 64 + kg * 16);
    f16x8 a1 = *(const f16x8*)(sm + SM_S0 + (rbase + 16 + arow) * ROWB + ks * 64 + kg * 16);
    #pragma unroll
    for (int tc = 0; tc < 8; ++tc) {
      f16x8 bf = *(const f16x8*)(sm + SM_R2 + (tc * 16 + arow) * ROWB + ks * 64 + kg * 16);
      acc2[0][tc] = __builtin_amdgcn_mfma_f32_16x16x32_f16(a0, bf, acc2[0][tc], 0, 0, 0);
      acc2[1][tc] = __builtin_amdgcn_mfma_f32_16x16x32_f16(a1, bf, acc2[1][tc], 0, 0, 0);
    }
  }
  // ---- P7: Y -> LDS f16 (own 32-row band of X region), then flush
  #pragma unroll
  for (int tr = 0; tr < 2; ++tr)
    #pragma unroll
    for (int tc = 0; tc < 8; ++tc)
      #pragma unroll
      for (int rg = 0; rg < 4; ++rg) {
        int row = rbase + tr * 16 + kg * 4 + rg;
        int col = tc * 16 + arow;
        *(_Float16*)(sm + SM_X + row * ROWB + col * 2) = (_Float16)acc2[tr][tc][rg];
      }
  __syncthreads();
  {
    char* dstb = (char*)Ytmp + (size_t)d * 32768;
    #pragma unroll
    for (int i = 0; i < 8; ++i) {
      int u = t + i * 256;
      int r = u >> 4, c16 = u & 15;
      *(uint4*)(dstb + r * 256 + c16 * 16) =
          *(const uint4*)(sm + SM_X + r * ROWB + c16 * 16);
    }
  }
}

// ---------------------------------------------------------------------------
// kcombine (round-6 vectorized version): out = Ytmp + X16*scale,
// uint2 global loads; float2 (8B) coalesced stores.
__global__ __launch_bounds__(256) void kcombine(
    const _Float16* __restrict__ Ytmp, const _Float16* __restrict__ X16,
    const float* __restrict__ input_scale, float* __restrict__ out) {
  __shared__ unsigned yl[64 * 65];
  __shared__ unsigned xl[64 * 65];
  int dg = blockIdx.x, m = blockIdx.y, b = blockIdx.z;
  int t = threadIdx.x;
  int d0 = dg * 64;
  #pragma unroll
  for (int it = 0; it < 8; ++it) {
    int idx = t + it * 256;            // 2048 uint2
    int r = idx >> 5, c2 = idx & 31;
    size_t dwoff = ((size_t)(d0 + r) * 128 + b * 16 + m) * 64 + c2 * 2;
    uint2 yv = *(const uint2*)((const unsigned*)Ytmp + dwoff);
    uint2 xv = *(const uint2*)((const unsigned*)X16 + dwoff);
    yl[r * 65 + c2 * 2] = yv.x; yl[r * 65 + c2 * 2 + 1] = yv.y;
    xl[r * 65 + c2 * 2] = xv.x; xl[r * 65 + c2 * 2 + 1] = xv.y;
  }
  __syncthreads();
  int dp = t & 31, jg = t >> 5;
  float sc0 = input_scale[d0 + 2 * dp], sc1 = input_scale[d0 + 2 * dp + 1];
  #pragma unroll
  for (int q = 0; q < 16; ++q) {
    int jj = jg * 16 + q;
    float y0 = (float)((const _Float16*)(yl + (2 * dp) * 65))[jj];
    float y1 = (float)((const _Float16*)(yl + (2 * dp + 1) * 65))[jj];
    float x0 = (float)((const _Float16*)(xl + (2 * dp) * 65))[jj];
    float x1 = (float)((const _Float16*)(xl + (2 * dp + 1) * 65))[jj];
    float2 o; o.x = y0 + x0 * sc0; o.y = y1 + x1 * sc1;
    *(float2*)(out + ((size_t)b * LL + m * 128 + jj) * DD + d0 + 2 * dp) = o;
  }
}

// ---------------------------------------------------------------------------
extern "C" void kernel_launch(void* const* d_in, const int* in_sizes, int n_in,
                              void* d_out, int out_size, void* d_ws, size_t ws_size,
                              hipStream_t stream) {
  const float* x           = (const float*)d_in[0];
  const float* log_dt      = (const float*)d_in[1];
  const float* log_a_real  = (const float*)d_in[2];
  const float* a_imag      = (const float*)d_in[3];
  const float* coeffs      = (const float*)d_in[4];
  const float* input_scale = (const float*)d_in[5];
  float* out = (float*)d_out;
  _Float16* X16  = (_Float16*)d_ws;
  _Float16* Ytmp = (_Float16*)((char*)d_ws + WS_YT_OFF);

  ktrans16<<<dim3(LL / 64, DD / 32, BB), 256, 0, stream>>>(x, X16);
  kfused<<<DD, 256, 0, stream>>>(X16, log_dt, log_a_real, a_imag, coeffs, Ytmp);
  kcombine<<<dim3(DD / 64, MCH, BB), 256, 0, stream>>>(Ytmp, X16, input_scale, out);
}